// Round 1
// baseline (2045.126 us; speedup 1.0000x reference)
//
#include <hip/hip_runtime.h>

#define I_SZ 256
#define H_SZ 512
#define O_SZ 256
#define B_SZ 4096
#define S_SZ 50
#define T_SZ 20

#define BK 64
#define PAD 72

typedef _Float16 half8 __attribute__((ext_vector_type(8)));
typedef float f32x4 __attribute__((ext_vector_type(4)));

__device__ __forceinline__ float sigm(float x) {
    return 1.0f / (1.0f + __expf(-x));
}
__device__ __forceinline__ float tanh_fast(float x) {
    float e = __expf(2.0f * x);
    return 1.0f - 2.0f / (e + 1.0f);
}

// ---------------- conversion kernels (run once per launch) ----------------
__global__ void k_f32_to_f16(const float* __restrict__ src, _Float16* __restrict__ dst, int n) {
    int i = blockIdx.x * blockDim.x + threadIdx.x;
    if (i < n) dst[i] = (_Float16)src[i];
}

__global__ void k_bias_combine(const float* __restrict__ a, const float* __restrict__ b,
                               float* __restrict__ dst, int n) {
    int i = blockIdx.x * blockDim.x + threadIdx.x;
    if (i < n) dst[i] = a[i] + b[i];
}

// ---------------- fused LSTM step ----------------
// gates = [x_t | h] @ [Wih | Whh]^T + bias ; cell update fused in epilogue.
// Block: 256 thr (4 waves). Tile: 128 batch rows x 32 hidden cols x 4 gates.
// Wave w handles rows [w*32, w*32+32), all 4 gates -> i/f/g/o of a cell live in one lane.
__global__ __launch_bounds__(256) void k_lstm_step(
    const float* __restrict__ xsrc,   // fp32 input rows (x_t or fed-back d_out slice); null -> skip
    int xld,                          // row stride (elements) of xsrc
    const _Float16* __restrict__ hin, // [B, H] fp16 (ignored if first)
    const _Float16* __restrict__ Wih, // [4H, I] fp16
    const _Float16* __restrict__ Whh, // [4H, H] fp16
    const float* __restrict__ bias,   // [4H] = bih + bhh
    _Float16* __restrict__ hout,      // [B, H]
    float* __restrict__ c,            // [B, H] fp32, in/out
    int first)                        // 1: h==0 (skip seg2), c==0 (no read)
{
    __shared__ _Float16 Asm[128][PAD];
    __shared__ _Float16 Bsm[128][PAD];

    const int tid  = threadIdx.x;
    const int m0   = blockIdx.x * 128;
    const int j0   = blockIdx.y * 32;
    const int wv   = tid >> 6;
    const int lane = tid & 63;
    const int lrow = lane & 15;
    const int lk   = (lane >> 4) * 8;

    f32x4 acc[2][4][2] = {};   // [m-frag][gate][j-frag]

    const int srow = tid >> 3;        // 0..31 staging row
    const int skc  = (tid & 7) * 8;   // 0..56 staging k-offset

    auto compute_tile = [&]() {
        #pragma unroll
        for (int kc = 0; kc < BK; kc += 32) {
            half8 a0 = *(const half8*)&Asm[wv * 32 + lrow][kc + lk];
            half8 a1 = *(const half8*)&Asm[wv * 32 + 16 + lrow][kc + lk];
            #pragma unroll
            for (int g = 0; g < 4; ++g) {
                #pragma unroll
                for (int jf = 0; jf < 2; ++jf) {
                    half8 b = *(const half8*)&Bsm[g * 32 + jf * 16 + lrow][kc + lk];
                    acc[0][g][jf] = __builtin_amdgcn_mfma_f32_16x16x32_f16(a0, b, acc[0][g][jf], 0, 0, 0);
                    acc[1][g][jf] = __builtin_amdgcn_mfma_f32_16x16x32_f16(a1, b, acc[1][g][jf], 0, 0, 0);
                }
            }
        }
    };

    // ---- segment 1: x_t @ Wih^T (K = 256), fp32 source converted in-flight ----
    if (xsrc) {
        for (int k0 = 0; k0 < I_SZ; k0 += BK) {
            __syncthreads();
            #pragma unroll
            for (int t = 0; t < 4; ++t) {
                int r = srow + t * 32;
                const float* p = xsrc + (size_t)(m0 + r) * xld + k0 + skc;
                float4 v0 = *(const float4*)p;
                float4 v1 = *(const float4*)(p + 4);
                half8 hv;
                hv[0] = (_Float16)v0.x; hv[1] = (_Float16)v0.y;
                hv[2] = (_Float16)v0.z; hv[3] = (_Float16)v0.w;
                hv[4] = (_Float16)v1.x; hv[5] = (_Float16)v1.y;
                hv[6] = (_Float16)v1.z; hv[7] = (_Float16)v1.w;
                *(half8*)&Asm[r][skc] = hv;
            }
            #pragma unroll
            for (int t = 0; t < 4; ++t) {
                int rr = srow + t * 32;
                int wrow = (rr >> 5) * H_SZ + j0 + (rr & 31);   // gate*H + j
                *(half8*)&Bsm[rr][skc] =
                    *(const half8*)(Wih + (size_t)wrow * I_SZ + k0 + skc);
            }
            __syncthreads();
            compute_tile();
        }
    }

    // ---- segment 2: h @ Whh^T (K = 512) ----
    if (!first) {
        for (int k0 = 0; k0 < H_SZ; k0 += BK) {
            __syncthreads();
            #pragma unroll
            for (int t = 0; t < 4; ++t) {
                int r = srow + t * 32;
                *(half8*)&Asm[r][skc] =
                    *(const half8*)(hin + (size_t)(m0 + r) * H_SZ + k0 + skc);
            }
            #pragma unroll
            for (int t = 0; t < 4; ++t) {
                int rr = srow + t * 32;
                int wrow = (rr >> 5) * H_SZ + j0 + (rr & 31);
                *(half8*)&Bsm[rr][skc] =
                    *(const half8*)(Whh + (size_t)wrow * H_SZ + k0 + skc);
            }
            __syncthreads();
            compute_tile();
        }
    }

    // ---- epilogue: bias + activations + cell update ----
    float bj[4][2];
    #pragma unroll
    for (int g = 0; g < 4; ++g)
        #pragma unroll
        for (int jf = 0; jf < 2; ++jf)
            bj[g][jf] = bias[g * H_SZ + j0 + jf * 16 + lrow];

    #pragma unroll
    for (int mi = 0; mi < 2; ++mi) {
        #pragma unroll
        for (int jf = 0; jf < 2; ++jf) {
            #pragma unroll
            for (int r = 0; r < 4; ++r) {
                int m = m0 + wv * 32 + mi * 16 + (lane >> 4) * 4 + r;
                int j = j0 + jf * 16 + lrow;
                float gi = acc[mi][0][jf][r] + bj[0][jf];
                float gf = acc[mi][1][jf][r] + bj[1][jf];
                float gg = acc[mi][2][jf][r] + bj[2][jf];
                float go = acc[mi][3][jf][r] + bj[3][jf];
                float iv = sigm(gi);
                float fv = sigm(gf);
                float gv = tanh_fast(gg);
                float ov = sigm(go);
                size_t idx = (size_t)m * H_SZ + j;
                float cold = first ? 0.0f : c[idx];
                float cn = fv * cold + iv * gv;
                c[idx] = cn;
                hout[idx] = (_Float16)(ov * tanh_fast(cn));
            }
        }
    }
}

// ---------------- FC: out = h @ fcW^T + b, written into d_out[:, t, :] ----------------
__global__ __launch_bounds__(256) void k_fc(
    const _Float16* __restrict__ h,   // [B, H]
    const _Float16* __restrict__ W,   // [O, H]
    const float* __restrict__ bias,   // [O]
    float* __restrict__ out,          // d_out + t*O
    int outld)                        // T*O
{
    __shared__ _Float16 Asm[128][PAD];
    __shared__ _Float16 Bsm[64][PAD];

    const int tid  = threadIdx.x;
    const int m0   = blockIdx.x * 128;
    const int o0   = blockIdx.y * 64;
    const int wv   = tid >> 6;
    const int lane = tid & 63;
    const int lrow = lane & 15;
    const int lk   = (lane >> 4) * 8;

    f32x4 acc[2][4] = {};   // [m-frag][n-frag]

    const int srow = tid >> 3;
    const int skc  = (tid & 7) * 8;

    for (int k0 = 0; k0 < H_SZ; k0 += BK) {
        __syncthreads();
        #pragma unroll
        for (int t = 0; t < 4; ++t) {
            int r = srow + t * 32;
            *(half8*)&Asm[r][skc] =
                *(const half8*)(h + (size_t)(m0 + r) * H_SZ + k0 + skc);
        }
        #pragma unroll
        for (int t = 0; t < 2; ++t) {
            int rr = srow + t * 32;
            *(half8*)&Bsm[rr][skc] =
                *(const half8*)(W + (size_t)(o0 + rr) * H_SZ + k0 + skc);
        }
        __syncthreads();
        #pragma unroll
        for (int kc = 0; kc < BK; kc += 32) {
            half8 a0 = *(const half8*)&Asm[wv * 32 + lrow][kc + lk];
            half8 a1 = *(const half8*)&Asm[wv * 32 + 16 + lrow][kc + lk];
            #pragma unroll
            for (int nf = 0; nf < 4; ++nf) {
                half8 b = *(const half8*)&Bsm[nf * 16 + lrow][kc + lk];
                acc[0][nf] = __builtin_amdgcn_mfma_f32_16x16x32_f16(a0, b, acc[0][nf], 0, 0, 0);
                acc[1][nf] = __builtin_amdgcn_mfma_f32_16x16x32_f16(a1, b, acc[1][nf], 0, 0, 0);
            }
        }
    }

    #pragma unroll
    for (int mi = 0; mi < 2; ++mi)
        #pragma unroll
        for (int nf = 0; nf < 4; ++nf)
            #pragma unroll
            for (int r = 0; r < 4; ++r) {
                int m = m0 + wv * 32 + mi * 16 + (lane >> 4) * 4 + r;
                int n = o0 + nf * 16 + lrow;
                out[(size_t)m * outld + n] = acc[mi][nf][r] + bias[n];
            }
}

extern "C" void kernel_launch(void* const* d_in, const int* in_sizes, int n_in,
                              void* d_out, int out_size, void* d_ws, size_t ws_size,
                              hipStream_t stream) {
    (void)in_sizes; (void)n_in; (void)out_size; (void)ws_size;

    const float* x    = (const float*)d_in[0];
    const float* eWih = (const float*)d_in[1];
    const float* eWhh = (const float*)d_in[2];
    const float* ebih = (const float*)d_in[3];
    const float* ebhh = (const float*)d_in[4];
    const float* dWih = (const float*)d_in[5];
    const float* dWhh = (const float*)d_in[6];
    const float* dbih = (const float*)d_in[7];
    const float* dbhh = (const float*)d_in[8];
    const float* fcW  = (const float*)d_in[9];
    const float* fcb  = (const float*)d_in[10];
    float* out = (float*)d_out;
    char* ws = (char*)d_ws;

    size_t off = 0;
    auto alloc = [&](size_t bytes) -> void* {
        void* p = ws + off;
        off += (bytes + 255) & ~(size_t)255;
        return p;
    };
    _Float16* eWih_h = (_Float16*)alloc((size_t)4 * H_SZ * I_SZ * 2);
    _Float16* eWhh_h = (_Float16*)alloc((size_t)4 * H_SZ * H_SZ * 2);
    _Float16* dWih_h = (_Float16*)alloc((size_t)4 * H_SZ * I_SZ * 2);
    _Float16* dWhh_h = (_Float16*)alloc((size_t)4 * H_SZ * H_SZ * 2);
    _Float16* fcW_h  = (_Float16*)alloc((size_t)O_SZ * H_SZ * 2);
    float*    eb     = (float*)alloc(4 * H_SZ * 4);
    float*    db     = (float*)alloc(4 * H_SZ * 4);
    _Float16* h0     = (_Float16*)alloc((size_t)B_SZ * H_SZ * 2);
    _Float16* h1     = (_Float16*)alloc((size_t)B_SZ * H_SZ * 2);
    float*    cbuf   = (float*)alloc((size_t)B_SZ * H_SZ * 4);

    const int nWih = 4 * H_SZ * I_SZ;   // 524288
    const int nWhh = 4 * H_SZ * H_SZ;   // 1048576
    const int nFc  = O_SZ * H_SZ;       // 131072

    k_f32_to_f16<<<(nWih + 255) / 256, 256, 0, stream>>>(eWih, eWih_h, nWih);
    k_f32_to_f16<<<(nWhh + 255) / 256, 256, 0, stream>>>(eWhh, eWhh_h, nWhh);
    k_f32_to_f16<<<(nWih + 255) / 256, 256, 0, stream>>>(dWih, dWih_h, nWih);
    k_f32_to_f16<<<(nWhh + 255) / 256, 256, 0, stream>>>(dWhh, dWhh_h, nWhh);
    k_f32_to_f16<<<(nFc  + 255) / 256, 256, 0, stream>>>(fcW, fcW_h, nFc);
    k_bias_combine<<<8, 256, 0, stream>>>(ebih, ebhh, eb, 4 * H_SZ);
    k_bias_combine<<<8, 256, 0, stream>>>(dbih, dbhh, db, 4 * H_SZ);

    dim3 gstep(B_SZ / 128, H_SZ / 32);
    dim3 blk(256);

    int step = 0;
    // ---- encoder ----
    for (int s = 0; s < S_SZ; ++s, ++step) {
        _Float16* hin  = (step & 1) ? h1 : h0;
        _Float16* hout = (step & 1) ? h0 : h1;
        k_lstm_step<<<gstep, blk, 0, stream>>>(
            x + (size_t)s * I_SZ, S_SZ * I_SZ,
            hin, eWih_h, eWhh_h, eb, hout, cbuf, s == 0 ? 1 : 0);
    }
    // ---- decoder ----
    for (int t = 0; t < T_SZ; ++t, ++step) {
        _Float16* hin  = (step & 1) ? h1 : h0;
        _Float16* hout = (step & 1) ? h0 : h1;
        const float* xs = (t == 0) ? nullptr : (out + (size_t)(t - 1) * O_SZ);
        k_lstm_step<<<gstep, blk, 0, stream>>>(
            xs, T_SZ * O_SZ,
            hin, dWih_h, dWhh_h, db, hout, cbuf, 0);
        k_fc<<<dim3(B_SZ / 128, O_SZ / 64), blk, 0, stream>>>(
            hout, fcW_h, fcb, out + (size_t)t * O_SZ, T_SZ * O_SZ);
    }
}